// Round 12
// baseline (58.205 us; speedup 1.0000x reference)
//
#include <hip/hip_runtime.h>

#define BATCH 4
#define NPTS  8192
#define BN    (BATCH * NPTS)   // 32768

typedef _Float16 f16;
typedef f16   f16x8  __attribute__((ext_vector_type(8)));
typedef float f32x16 __attribute__((ext_vector_type(16)));

// order-preserving float <-> uint for unsigned atomicMin
__device__ __forceinline__ unsigned fkey(float f) {
    unsigned u = __float_as_uint(f);
    return u ^ (unsigned)(((int)u >> 31) | 0x80000000);
}
__device__ __forceinline__ float funkey(unsigned k) {
    unsigned u = k ^ ((k & 0x80000000u) ? 0x80000000u : 0xFFFFFFFFu);
    return __uint_as_float(u);
}

// ---- pack+init: point -> f16x8 {-2x,-2y,-2z, csq_hi, csq_lo, 0,0,0} -------
// Also initializes keys (one word per thread), the zero page, and out.
// grid: (BN/256, 2) x 256
__global__ void pack_kernel(const float* __restrict__ preds,
                            const float* __restrict__ gts,
                            f16x8* __restrict__ cP,
                            f16x8* __restrict__ cG,
                            unsigned* __restrict__ keys,
                            f16x8* __restrict__ zp,
                            float* __restrict__ out) {
    const int i     = blockIdx.x * 256 + threadIdx.x;
    const int which = blockIdx.y;

    keys[(size_t)which * BN + i] = 0xFFFFFFFFu;   // +inf key

    if (which == 0 && i == 0) {
        *out = 0.0f;
        f16x8 z;
#pragma unroll
        for (int j = 0; j < 8; ++j) z[j] = (f16)0.0f;
        zp[0] = z; zp[1] = z;
    }

    const float* src = which ? gts : preds;
    f16x8* dst       = which ? cG : cP;
    float x = src[3 * i], y = src[3 * i + 1], z = src[3 * i + 2];
    f16 xh = (f16)x, yh = (f16)y, zh = (f16)z;
    float xf = (float)xh, yf = (float)yh, zf = (float)zh;
    float csq = xf * xf + yf * yf + zf * zf;
    f16 ch = (f16)csq;
    f16 cl = (f16)(csq - (float)ch);
    f16x8 v;
    v[0] = xh * (f16)(-2.0f);
    v[1] = yh * (f16)(-2.0f);
    v[2] = zh * (f16)(-2.0f);
    v[3] = ch;
    v[4] = cl;
    v[5] = (f16)0.0f; v[6] = (f16)0.0f; v[7] = (f16)0.0f;
    dst[i] = v;
}

// ---- main: MFMA pairwise distances, per-wave min, atomicMin merge ---------
// R8 structure (best measured: 2 A-frags, 4 MFMA per iteration) + unroll 2:
// per-wave time is iteration-LATENCY-bound (R11 halved work, stayed ~flat),
// so interleaving two iterations puts 4 loads in flight and hides the ~200cy
// L2 latency under the previous iteration's MFMA+min3 stream.
// grid: 1024 x 256. Wave: 64 queries (2 A-frags) x 2048 candidates.
// v_mfma_f32_32x32x16_f16: A 32x16 (lane: row=l&31, k=8*(l>>5)+j),
// B 16x32 (lane: col=l&31, k=8*(l>>5)+j), D: col=l&31, row=(r&3)+8*(r>>2)+4*(l>>5).
__global__ void __launch_bounds__(256, 4)
chamfer_mfma_kernel(const f16x8* __restrict__ cP,
                    const f16x8* __restrict__ cG,
                    const f16x8* __restrict__ zp,
                    unsigned* __restrict__ keys) {
    const int lane   = threadIdx.x & 63;
    const int wavein = threadIdx.x >> 6;

    const int bd  = blockIdx.x >> 7;            // 0..7 : b*2 + dir
    const int rem = blockIdx.x & 127;
    const int s   = rem & 3;                     // candidate split 0..3
    const int qt  = (rem >> 2) * 4 + wavein;     // query tile 0..127
    const int b   = bd >> 1;
    const int dir = bd & 1;                      // 0: q=preds,c=gts ; 1: swapped

    const f16x8* __restrict__ Q = dir ? cG : cP;
    const f16x8* __restrict__ C = dir ? cP : cG;

    const bool act = lane < 32;
    const int  l31 = lane & 31;

    // ---- A fragments: two 32-query tiles, transformed from candidate-form
    const int q0 = b * NPTS + qt * 64;
    const f16x8* pA0 = act ? (Q + q0 + l31)      : zp;
    const f16x8* pA1 = act ? (Q + q0 + 32 + l31) : zp;
    f16x8 a0r = *pA0;
    f16x8 a1r = *pA1;
    const f16 nh  = (f16)(-0.5f);                // -0.5 * (-2x) = x, exact
    const f16 one = act ? (f16)1.0f : (f16)0.0f;
    f16x8 a0, a1;
    a0[0] = a0r[0] * nh; a0[1] = a0r[1] * nh; a0[2] = a0r[2] * nh;
    a0[3] = one; a0[4] = one; a0[5] = (f16)0.0f; a0[6] = (f16)0.0f; a0[7] = (f16)0.0f;
    a1[0] = a1r[0] * nh; a1[1] = a1r[1] * nh; a1[2] = a1r[2] * nh;
    a1[3] = one; a1[4] = one; a1[5] = (f16)0.0f; a1[6] = (f16)0.0f; a1[7] = (f16)0.0f;

    // ---- candidate stream pointers (lanes >=32 pinned to zero page)
    const int c0 = b * NPTS + s * 2048;
    const f16x8* pB0 = act ? (C + c0 + l31)      : zp;
    const f16x8* pB1 = act ? (C + c0 + 32 + l31) : zp;
    const long step = act ? 64 : 0;              // in f16x8 elements

    f32x16 m0, m1, zacc;
#pragma unroll
    for (int i = 0; i < 16; ++i) { m0[i] = 1e30f; m1[i] = 1e30f; zacc[i] = 0.0f; }

#pragma unroll 2
    for (int it = 0; it < 32; ++it) {            // 32 iters x 64 candidates
        f16x8 b0 = *pB0;
        f16x8 b1 = *pB1;
        pB0 += step; pB1 += step;
        // D = csq - 2<q,c> (csq folded in via K-slots 3,4)
        f32x16 d00 = __builtin_amdgcn_mfma_f32_32x32x16_f16(a0, b0, zacc, 0, 0, 0);
        f32x16 d01 = __builtin_amdgcn_mfma_f32_32x32x16_f16(a0, b1, zacc, 0, 0, 0);
#pragma unroll
        for (int i = 0; i < 16; ++i)
            m0[i] = fminf(m0[i], fminf(d00[i], d01[i]));   // -> v_min3_f32
        f32x16 d10 = __builtin_amdgcn_mfma_f32_32x32x16_f16(a1, b0, zacc, 0, 0, 0);
        f32x16 d11 = __builtin_amdgcn_mfma_f32_32x32x16_f16(a1, b1, zacc, 0, 0, 0);
#pragma unroll
        for (int i = 0; i < 16; ++i)
            m1[i] = fminf(m1[i], fminf(d10[i], d11[i]));
    }

    // ---- cross-lane min over the 32 columns (candidates) of each row
#pragma unroll
    for (int i = 0; i < 16; ++i) {
        float v0 = m0[i], v1 = m1[i];
#pragma unroll
        for (int mask = 1; mask <= 16; mask <<= 1) {
            v0 = fminf(v0, __shfl_xor(v0, mask, 64));
            v1 = fminf(v1, __shfl_xor(v1, mask, 64));
        }
        m0[i] = v0; m1[i] = v1;
    }

    // ---- merge: lanes 0 and 32 own row-halves (row = (r&3)+8*(r>>2)+4*(lane>>5))
    if ((lane & 31) == 0) {
        unsigned* __restrict__ kout = keys + (size_t)dir * BN;
        const int rbase = q0 + ((lane >> 5) << 2);
#pragma unroll
        for (int r = 0; r < 16; ++r) {
            const int row = (r & 3) + 8 * (r >> 2);
            atomicMin(&kout[rbase + row],      fkey(m0[r]));
            atomicMin(&kout[rbase + 32 + row], fkey(m1[r]));
        }
    }
}

// ---- finalize: decode key, + qsq (from quantized pack), global sum --------
// grid: 2*BN/256 = 256 blocks
__global__ void __launch_bounds__(256)
finalize_kernel(const unsigned* __restrict__ keys,
                const f16x8* __restrict__ cP,
                const f16x8* __restrict__ cG,
                float* __restrict__ out) {
    __shared__ float red[4];
    const int idx = blockIdx.x * 256 + threadIdx.x;   // [0, 2*BN)
    const int dir = idx >> 15;
    const int q   = idx & (BN - 1);

    f16x8 v = (dir ? cG : cP)[q];                 // query's own pack
    const float qsq = (float)v[3] + (float)v[4];  // csq_hi + csq_lo
    float val = funkey(keys[idx]) + qsq;

#pragma unroll
    for (int off = 32; off > 0; off >>= 1)
        val += __shfl_down(val, off, 64);

    const int wave = threadIdx.x >> 6;
    const int lane = threadIdx.x & 63;
    if (lane == 0) red[wave] = val;
    __syncthreads();
    if (threadIdx.x == 0)
        atomicAdd(out, red[0] + red[1] + red[2] + red[3]);
}

extern "C" void kernel_launch(void* const* d_in, const int* in_sizes, int n_in,
                              void* d_out, int out_size, void* d_ws, size_t ws_size,
                              hipStream_t stream) {
    const float* preds = (const float*)d_in[0];
    const float* gts   = (const float*)d_in[1];
    float* out = (float*)d_out;

    // ws layout: zeropage 256B | keys 256KB | cPackP 512KB | cPackG 512KB
    char* ws = (char*)d_ws;
    f16x8*    zp   = (f16x8*)ws;
    unsigned* keys = (unsigned*)(ws + 256);
    f16x8*    cP   = (f16x8*)(ws + 256 + (size_t)2 * BN * 4);
    f16x8*    cG   = cP + BN;

    dim3 gpack(BN / 256, 2);
    pack_kernel<<<gpack, 256, 0, stream>>>(preds, gts, cP, cG, keys, zp, out);

    chamfer_mfma_kernel<<<1024, 256, 0, stream>>>(cP, cG, zp, keys);

    finalize_kernel<<<2 * BN / 256, 256, 0, stream>>>(keys, cP, cG, out);
}

// Round 13
// 44.426 us; speedup vs baseline: 1.3102x; 1.3102x over previous
//
#include <hip/hip_runtime.h>

#define BATCH 4
#define NPTS  8192
#define BN    (BATCH * NPTS)   // 32768

typedef _Float16 f16;
typedef f16   f16x8  __attribute__((ext_vector_type(8)));
typedef float f32x16 __attribute__((ext_vector_type(16)));

// order-preserving float <-> uint for unsigned atomicMin
__device__ __forceinline__ unsigned fkey(float f) {
    unsigned u = __float_as_uint(f);
    return u ^ (unsigned)(((int)u >> 31) | 0x80000000);
}
__device__ __forceinline__ float funkey(unsigned k) {
    unsigned u = k ^ ((k & 0x80000000u) ? 0x80000000u : 0xFFFFFFFFu);
    return __uint_as_float(u);
}

// ---- pack+init: point -> f16x8 {-2x,-2y,-2z, csq_hi, csq_lo, 0,0,0} -------
// Also initializes keys (one word per thread), the zero page, and out.
// grid: (BN/256, 2) x 256
__global__ void pack_kernel(const float* __restrict__ preds,
                            const float* __restrict__ gts,
                            f16x8* __restrict__ cP,
                            f16x8* __restrict__ cG,
                            unsigned* __restrict__ keys,
                            f16x8* __restrict__ zp,
                            float* __restrict__ out) {
    const int i     = blockIdx.x * 256 + threadIdx.x;
    const int which = blockIdx.y;

    keys[(size_t)which * BN + i] = 0xFFFFFFFFu;   // +inf key

    if (which == 0 && i == 0) {
        *out = 0.0f;
        f16x8 z;
#pragma unroll
        for (int j = 0; j < 8; ++j) z[j] = (f16)0.0f;
        zp[0] = z; zp[1] = z;
    }

    const float* src = which ? gts : preds;
    f16x8* dst       = which ? cG : cP;
    float x = src[3 * i], y = src[3 * i + 1], z = src[3 * i + 2];
    f16 xh = (f16)x, yh = (f16)y, zh = (f16)z;
    float xf = (float)xh, yf = (float)yh, zf = (float)zh;
    float csq = xf * xf + yf * yf + zf * zf;
    f16 ch = (f16)csq;
    f16 cl = (f16)(csq - (float)ch);
    f16x8 v;
    v[0] = xh * (f16)(-2.0f);
    v[1] = yh * (f16)(-2.0f);
    v[2] = zh * (f16)(-2.0f);
    v[3] = ch;
    v[4] = cl;
    v[5] = (f16)0.0f; v[6] = (f16)0.0f; v[7] = (f16)0.0f;
    dst[i] = v;
}

// ---- main: MFMA pairwise distances, per-wave min, atomicMin merge ---------
// EXACT R8 wave body (2 A-frags, 4 MFMA/iter, NO unroll pragma -- R12 showed
// unroll 2 doubles live accumulator tiles -> AGPR traffic, 30us -> 49us).
// Only change vs R8: candidate split S 4 -> 8, grid 1024 -> 2048, so 8
// blocks/CU = 8 waves/SIMD hide per-iteration load->MFMA->min latency.
// grid: 2048 x 256. Wave: 64 queries (2 A-frags) x 1024 candidates, 16 iters.
// v_mfma_f32_32x32x16_f16: A 32x16 (lane: row=l&31, k=8*(l>>5)+j),
// B 16x32 (lane: col=l&31, k=8*(l>>5)+j), D: col=l&31, row=(r&3)+8*(r>>2)+4*(l>>5).
__global__ void __launch_bounds__(256, 4)
chamfer_mfma_kernel(const f16x8* __restrict__ cP,
                    const f16x8* __restrict__ cG,
                    const f16x8* __restrict__ zp,
                    unsigned* __restrict__ keys) {
    const int lane   = threadIdx.x & 63;
    const int wavein = threadIdx.x >> 6;

    const int bd  = blockIdx.x >> 8;            // 0..7 : b*2 + dir
    const int rem = blockIdx.x & 255;
    const int s   = rem & 7;                     // candidate split 0..7
    const int qt  = (rem >> 3) * 4 + wavein;     // query tile 0..127
    const int b   = bd >> 1;
    const int dir = bd & 1;                      // 0: q=preds,c=gts ; 1: swapped

    const f16x8* __restrict__ Q = dir ? cG : cP;
    const f16x8* __restrict__ C = dir ? cP : cG;

    const bool act = lane < 32;
    const int  l31 = lane & 31;

    // ---- A fragments: two 32-query tiles, transformed from candidate-form
    const int q0 = b * NPTS + qt * 64;
    const f16x8* pA0 = act ? (Q + q0 + l31)      : zp;
    const f16x8* pA1 = act ? (Q + q0 + 32 + l31) : zp;
    f16x8 a0r = *pA0;
    f16x8 a1r = *pA1;
    const f16 nh  = (f16)(-0.5f);                // -0.5 * (-2x) = x, exact
    const f16 one = act ? (f16)1.0f : (f16)0.0f;
    f16x8 a0, a1;
    a0[0] = a0r[0] * nh; a0[1] = a0r[1] * nh; a0[2] = a0r[2] * nh;
    a0[3] = one; a0[4] = one; a0[5] = (f16)0.0f; a0[6] = (f16)0.0f; a0[7] = (f16)0.0f;
    a1[0] = a1r[0] * nh; a1[1] = a1r[1] * nh; a1[2] = a1r[2] * nh;
    a1[3] = one; a1[4] = one; a1[5] = (f16)0.0f; a1[6] = (f16)0.0f; a1[7] = (f16)0.0f;

    // ---- candidate stream pointers (lanes >=32 pinned to zero page)
    const int c0 = b * NPTS + s * 1024;
    const f16x8* pB0 = act ? (C + c0 + l31)      : zp;
    const f16x8* pB1 = act ? (C + c0 + 32 + l31) : zp;
    const long step = act ? 64 : 0;              // in f16x8 elements

    f32x16 m0, m1, zacc;
#pragma unroll
    for (int i = 0; i < 16; ++i) { m0[i] = 1e30f; m1[i] = 1e30f; zacc[i] = 0.0f; }

    for (int it = 0; it < 16; ++it) {            // 16 iters x 64 candidates
        f16x8 b0 = *pB0;
        f16x8 b1 = *pB1;
        pB0 += step; pB1 += step;
        // D = csq - 2<q,c> (csq folded in via K-slots 3,4)
        f32x16 d00 = __builtin_amdgcn_mfma_f32_32x32x16_f16(a0, b0, zacc, 0, 0, 0);
        f32x16 d01 = __builtin_amdgcn_mfma_f32_32x32x16_f16(a0, b1, zacc, 0, 0, 0);
#pragma unroll
        for (int i = 0; i < 16; ++i)
            m0[i] = fminf(m0[i], fminf(d00[i], d01[i]));   // -> v_min3_f32
        f32x16 d10 = __builtin_amdgcn_mfma_f32_32x32x16_f16(a1, b0, zacc, 0, 0, 0);
        f32x16 d11 = __builtin_amdgcn_mfma_f32_32x32x16_f16(a1, b1, zacc, 0, 0, 0);
#pragma unroll
        for (int i = 0; i < 16; ++i)
            m1[i] = fminf(m1[i], fminf(d10[i], d11[i]));
    }

    // ---- cross-lane min over the 32 columns (candidates) of each row
#pragma unroll
    for (int i = 0; i < 16; ++i) {
        float v0 = m0[i], v1 = m1[i];
#pragma unroll
        for (int mask = 1; mask <= 16; mask <<= 1) {
            v0 = fminf(v0, __shfl_xor(v0, mask, 64));
            v1 = fminf(v1, __shfl_xor(v1, mask, 64));
        }
        m0[i] = v0; m1[i] = v1;
    }

    // ---- merge: lanes 0 and 32 own row-halves (row = (r&3)+8*(r>>2)+4*(lane>>5))
    if ((lane & 31) == 0) {
        unsigned* __restrict__ kout = keys + (size_t)dir * BN;
        const int rbase = q0 + ((lane >> 5) << 2);
#pragma unroll
        for (int r = 0; r < 16; ++r) {
            const int row = (r & 3) + 8 * (r >> 2);
            atomicMin(&kout[rbase + row],      fkey(m0[r]));
            atomicMin(&kout[rbase + 32 + row], fkey(m1[r]));
        }
    }
}

// ---- finalize: decode key, + qsq (from quantized pack), global sum --------
// grid: 2*BN/256 = 256 blocks
__global__ void __launch_bounds__(256)
finalize_kernel(const unsigned* __restrict__ keys,
                const f16x8* __restrict__ cP,
                const f16x8* __restrict__ cG,
                float* __restrict__ out) {
    __shared__ float red[4];
    const int idx = blockIdx.x * 256 + threadIdx.x;   // [0, 2*BN)
    const int dir = idx >> 15;
    const int q   = idx & (BN - 1);

    f16x8 v = (dir ? cG : cP)[q];                 // query's own pack
    const float qsq = (float)v[3] + (float)v[4];  // csq_hi + csq_lo
    float val = funkey(keys[idx]) + qsq;

#pragma unroll
    for (int off = 32; off > 0; off >>= 1)
        val += __shfl_down(val, off, 64);

    const int wave = threadIdx.x >> 6;
    const int lane = threadIdx.x & 63;
    if (lane == 0) red[wave] = val;
    __syncthreads();
    if (threadIdx.x == 0)
        atomicAdd(out, red[0] + red[1] + red[2] + red[3]);
}

extern "C" void kernel_launch(void* const* d_in, const int* in_sizes, int n_in,
                              void* d_out, int out_size, void* d_ws, size_t ws_size,
                              hipStream_t stream) {
    const float* preds = (const float*)d_in[0];
    const float* gts   = (const float*)d_in[1];
    float* out = (float*)d_out;

    // ws layout: zeropage 256B | keys 256KB | cPackP 512KB | cPackG 512KB
    char* ws = (char*)d_ws;
    f16x8*    zp   = (f16x8*)ws;
    unsigned* keys = (unsigned*)(ws + 256);
    f16x8*    cP   = (f16x8*)(ws + 256 + (size_t)2 * BN * 4);
    f16x8*    cG   = cP + BN;

    dim3 gpack(BN / 256, 2);
    pack_kernel<<<gpack, 256, 0, stream>>>(preds, gts, cP, cG, keys, zp, out);

    chamfer_mfma_kernel<<<2048, 256, 0, stream>>>(cP, cG, zp, keys);

    finalize_kernel<<<2 * BN / 256, 256, 0, stream>>>(keys, cP, cG, out);
}

// Round 14
// 37.025 us; speedup vs baseline: 1.5720x; 1.1999x over previous
//
#include <hip/hip_runtime.h>

#define BATCH 4
#define NPTS  8192
#define BN    (BATCH * NPTS)   // 32768

typedef _Float16 f16;
typedef f16   f16x8  __attribute__((ext_vector_type(8)));
typedef float f32x16 __attribute__((ext_vector_type(16)));

// order-preserving float <-> uint for unsigned atomicMin
__device__ __forceinline__ unsigned fkey(float f) {
    unsigned u = __float_as_uint(f);
    return u ^ (unsigned)(((int)u >> 31) | 0x80000000);
}
__device__ __forceinline__ float funkey(unsigned k) {
    unsigned u = k ^ ((k & 0x80000000u) ? 0x80000000u : 0xFFFFFFFFu);
    return __uint_as_float(u);
}

// ---- pack+init: point -> f16x8 {-2x,-2y,-2z, csq_hi, csq_lo, 0,0,0} -------
// Also initializes keys (one word per thread), the zero page, and out.
// grid: (BN/256, 2) x 256
__global__ void pack_kernel(const float* __restrict__ preds,
                            const float* __restrict__ gts,
                            f16x8* __restrict__ cP,
                            f16x8* __restrict__ cG,
                            unsigned* __restrict__ keys,
                            f16x8* __restrict__ zp,
                            float* __restrict__ out) {
    const int i     = blockIdx.x * 256 + threadIdx.x;
    const int which = blockIdx.y;

    keys[(size_t)which * BN + i] = 0xFFFFFFFFu;   // +inf key

    if (which == 0 && i == 0) {
        *out = 0.0f;
        f16x8 z;
#pragma unroll
        for (int j = 0; j < 8; ++j) z[j] = (f16)0.0f;
        zp[0] = z; zp[1] = z;
    }

    const float* src = which ? gts : preds;
    f16x8* dst       = which ? cG : cP;
    float x = src[3 * i], y = src[3 * i + 1], z = src[3 * i + 2];
    f16 xh = (f16)x, yh = (f16)y, zh = (f16)z;
    float xf = (float)xh, yf = (float)yh, zf = (float)zh;
    float csq = xf * xf + yf * yf + zf * zf;
    f16 ch = (f16)csq;
    f16 cl = (f16)(csq - (float)ch);
    f16x8 v;
    v[0] = xh * (f16)(-2.0f);
    v[1] = yh * (f16)(-2.0f);
    v[2] = zh * (f16)(-2.0f);
    v[3] = ch;
    v[4] = cl;
    v[5] = (f16)0.0f; v[6] = (f16)0.0f; v[7] = (f16)0.0f;
    dst[i] = v;
}

// ---- main: A=candidates (streamed), B=queries (fixed 32) ------------------
// D[c,q] = csq - 2<q,c>; lane owns query col l&31 and 16 CANDIDATE rows ->
// per-iter min collapses IN-REGISTER (8 v_min3) into one scalar m.
// Epilogue: 1 shfl_xor(32) + 1 atomicMin  (R8's was 160 shuffles: its main
// cost). Live regs ~50 -> 8 waves/SIMD at 8 blocks/CU.
// grid: 2048 x 256. Wave: 32 queries x 2048 candidates, 64 iters.
// v_mfma_f32_32x32x16_f16: A 32x16 (lane: row=l&31, k=8*(l>>5)+j),
// B 16x32 (lane: col=l&31, k=8*(l>>5)+j), D: col=l&31, row=(r&3)+8*(r>>2)+4*(l>>5).
__global__ void __launch_bounds__(256, 4)
chamfer_mfma_kernel(const f16x8* __restrict__ cP,
                    const f16x8* __restrict__ cG,
                    const f16x8* __restrict__ zp,
                    unsigned* __restrict__ keys) {
    const int lane   = threadIdx.x & 63;
    const int wavein = threadIdx.x >> 6;

    const int s   = blockIdx.x & 3;              // candidate split 0..3
    const int qg  = (blockIdx.x >> 2) & 63;      // query group 0..63
    const int bd  = blockIdx.x >> 8;             // b*2 + dir, 0..7
    const int b   = bd >> 1;
    const int dir = bd & 1;                      // 0: q=preds,c=gts ; 1: swapped

    const f16x8* __restrict__ Q = dir ? cG : cP;
    const f16x8* __restrict__ C = dir ? cP : cG;

    const bool hi  = lane >= 32;                 // k-half 1: all-zero slots
    const int  l31 = lane & 31;

    // ---- B fragment: 32 fixed queries {qx,qy,qz,1,1,0,0,0}; hi lanes zero
    const int q0 = b * NPTS + (qg * 4 + wavein) * 32;
    f16x8 bq;
    {
        const f16x8* pQ = hi ? zp : (Q + q0 + l31);
        f16x8 qr = *pQ;
        const f16 nh  = (f16)(-0.5f);            // -0.5 * (-2x) = x, exact
        const f16 one = hi ? (f16)0.0f : (f16)1.0f;
        bq[0] = qr[0] * nh; bq[1] = qr[1] * nh; bq[2] = qr[2] * nh;
        bq[3] = one; bq[4] = one;
        bq[5] = (f16)0.0f; bq[6] = (f16)0.0f; bq[7] = (f16)0.0f;
    }

    // ---- A stream: candidate tiles, raw pack; hi lanes pinned to zero page
    const int c0 = b * NPTS + s * 2048;
    const f16x8* pA  = hi ? zp : (C + c0 + l31);
    const long  step = hi ? 0 : 32;              // 32 candidates per iter

    f32x16 zacc;
#pragma unroll
    for (int i = 0; i < 16; ++i) zacc[i] = 0.0f;
    float m = 1e30f;

    for (int it = 0; it < 64; ++it) {            // 64 iters x 32 candidates
        f16x8 a = *pA;
        pA += step;
        // D[cand,query] = csq - 2<q,c> (csq folded via K-slots 3,4)
        f32x16 d = __builtin_amdgcn_mfma_f32_32x32x16_f16(a, bq, zacc, 0, 0, 0);
        // in-register min over the 16 candidate rows -> v_min3 tree
        float t0 = fminf(fminf(d[0],  d[1]),  d[2]);
        float t1 = fminf(fminf(d[3],  d[4]),  d[5]);
        float t2 = fminf(fminf(d[6],  d[7]),  d[8]);
        float t3 = fminf(fminf(d[9],  d[10]), d[11]);
        float t4 = fminf(fminf(d[12], d[13]), d[14]);
        float t5 = fminf(fminf(t0, t1), d[15]);
        float t6 = fminf(fminf(t2, t3), t4);
        m = fminf(m, fminf(t5, t6));
    }

    // ---- epilogue: merge the two candidate-row halves, one atomic ---------
    m = fminf(m, __shfl_xor(m, 32, 64));
    if (!hi)
        atomicMin(&keys[(size_t)dir * BN + q0 + l31], fkey(m));
}

// ---- finalize: decode key, + qsq (from quantized pack), global sum --------
// grid: 2*BN/256 = 256 blocks
__global__ void __launch_bounds__(256)
finalize_kernel(const unsigned* __restrict__ keys,
                const f16x8* __restrict__ cP,
                const f16x8* __restrict__ cG,
                float* __restrict__ out) {
    __shared__ float red[4];
    const int idx = blockIdx.x * 256 + threadIdx.x;   // [0, 2*BN)
    const int dir = idx >> 15;
    const int q   = idx & (BN - 1);

    f16x8 v = (dir ? cG : cP)[q];                 // query's own pack
    const float qsq = (float)v[3] + (float)v[4];  // csq_hi + csq_lo
    float val = funkey(keys[idx]) + qsq;

#pragma unroll
    for (int off = 32; off > 0; off >>= 1)
        val += __shfl_down(val, off, 64);

    const int wave = threadIdx.x >> 6;
    const int lane = threadIdx.x & 63;
    if (lane == 0) red[wave] = val;
    __syncthreads();
    if (threadIdx.x == 0)
        atomicAdd(out, red[0] + red[1] + red[2] + red[3]);
}

extern "C" void kernel_launch(void* const* d_in, const int* in_sizes, int n_in,
                              void* d_out, int out_size, void* d_ws, size_t ws_size,
                              hipStream_t stream) {
    const float* preds = (const float*)d_in[0];
    const float* gts   = (const float*)d_in[1];
    float* out = (float*)d_out;

    // ws layout: zeropage 256B | keys 256KB | cPackP 512KB | cPackG 512KB
    char* ws = (char*)d_ws;
    f16x8*    zp   = (f16x8*)ws;
    unsigned* keys = (unsigned*)(ws + 256);
    f16x8*    cP   = (f16x8*)(ws + 256 + (size_t)2 * BN * 4);
    f16x8*    cG   = cP + BN;

    dim3 gpack(BN / 256, 2);
    pack_kernel<<<gpack, 256, 0, stream>>>(preds, gts, cP, cG, keys, zp, out);

    chamfer_mfma_kernel<<<2048, 256, 0, stream>>>(cP, cG, zp, keys);

    finalize_kernel<<<2 * BN / 256, 256, 0, stream>>>(keys, cP, cG, out);
}